// Round 2
// baseline (89.676 us; speedup 1.0000x reference)
//
#include <hip/hip_runtime.h>

// MIL loss, Y==1 path collapses to:
//   result = sum_e w[e] * ( S0 + sum_{set bits k of (e+1)} d[19-k] )
// with S0 = sum_j log(1-p_j), d[j] = log(p_j) - log(1-p_j).
// Y!=1 path: result = (2^20-1) * sum_j log(1-p_j).

#define N_BITS    20
#define N_SUBSETS ((1u << N_BITS) - 1u)   // 1048575
#define NBLOCKS   1024
#define NTHREADS  256

__global__ __launch_bounds__(NTHREADS) void mil_loss_kernel(
    const float* __restrict__ y_prob,
    const float* __restrict__ w,
    const int*   __restrict__ Yp,
    float*       __restrict__ out,
    double*      __restrict__ ws_acc,
    unsigned int* __restrict__ ws_cnt)
{
    __shared__ float s_lp[N_BITS];
    __shared__ float s_l1[N_BITS];
    __shared__ float t_lo[1024];
    __shared__ float t_hi[1024];
    __shared__ double s_wsum[NTHREADS / 64];

    const int tid = threadIdx.x;

    // --- logs of the 20 probabilities ---
    if (tid < N_BITS) {
        float p = y_prob[tid];
        s_lp[tid] = logf(p);
        s_l1[tid] = logf(1.0f - p);
    }
    __syncthreads();

    // --- build the two 10-bit lookup tables (4 entries per thread each) ---
    for (int m = tid; m < 1024; m += NTHREADS) {
        float alo = 0.0f, ahi = 0.0f;
        #pragma unroll
        for (int k = 0; k < 10; ++k) {
            if ((m >> k) & 1) {
                alo += s_lp[19 - k] - s_l1[19 - k];  // idx bits 0..9  -> col 19-k
                ahi += s_lp[9 - k]  - s_l1[9 - k];   // idx bits 10..19 -> col 9-k
            }
        }
        t_lo[m] = alo;
        t_hi[m] = ahi;
    }

    // S0 computed redundantly per thread (20 adds, trivial)
    float S0 = 0.0f;
    #pragma unroll
    for (int j = 0; j < N_BITS; ++j) S0 += s_l1[j];
    __syncthreads();

    // --- main dot: each thread owns 4 consecutive elements, float4 load ---
    const unsigned e0 = ((unsigned)blockIdx.x * NTHREADS + (unsigned)tid) * 4u;
    double acc = 0.0;
    if (e0 + 3u < N_SUBSETS) {
        const float4 wv = *reinterpret_cast<const float4*>(w + e0);
        unsigned i0 = e0 + 1u, i1 = e0 + 2u, i2 = e0 + 3u, i3 = e0 + 4u;
        float v0 = S0 + t_hi[i0 >> 10] + t_lo[i0 & 1023u];
        float v1 = S0 + t_hi[i1 >> 10] + t_lo[i1 & 1023u];
        float v2 = S0 + t_hi[i2 >> 10] + t_lo[i2 & 1023u];
        float v3 = S0 + t_hi[i3 >> 10] + t_lo[i3 & 1023u];
        acc = (double)(v0 * wv.x) + (double)(v1 * wv.y)
            + (double)(v2 * wv.z) + (double)(v3 * wv.w);
    } else {
        #pragma unroll
        for (unsigned r = 0; r < 4u; ++r) {
            unsigned e = e0 + r;
            if (e < N_SUBSETS) {
                unsigned idx = e + 1u;
                acc += (double)((S0 + t_hi[idx >> 10] + t_lo[idx & 1023u]) * w[e]);
            }
        }
    }

    // --- block reduction (wave shuffle, then 4 wave partials) ---
    #pragma unroll
    for (int off = 32; off > 0; off >>= 1)
        acc += __shfl_down(acc, off, 64);
    const int wid = tid >> 6, lane = tid & 63;
    if (lane == 0) s_wsum[wid] = acc;
    __syncthreads();

    if (tid == 0) {
        double bsum = s_wsum[0] + s_wsum[1] + s_wsum[2] + s_wsum[3];
        atomicAdd(ws_acc, bsum);
        __threadfence();
        unsigned prev = atomicAdd(ws_cnt, 1u);
        if (prev == (unsigned)(NBLOCKS - 1)) {
            // last block: all partials are visible (fenced before each counter inc)
            double total = atomicAdd(ws_acc, 0.0);  // coherent read via RMW
            int Y = *Yp;
            float result;
            if (Y == 1) {
                result = (float)total;
            } else {
                float s1 = 0.0f;
                #pragma unroll
                for (int j = 0; j < N_BITS; ++j) s1 += s_l1[j];
                result = (float)N_SUBSETS * s1;
            }
            *out = result;
        }
    }
}

extern "C" void kernel_launch(void* const* d_in, const int* in_sizes, int n_in,
                              void* d_out, int out_size, void* d_ws, size_t ws_size,
                              hipStream_t stream) {
    const float* y_prob = (const float*)d_in[0];
    const float* w      = (const float*)d_in[1];
    const int*   Y      = (const int*)d_in[2];
    // d_in[3] = bag_size (fixed at 20, baked into N_BITS)
    float* out = (float*)d_out;

    double*       ws_acc = (double*)d_ws;
    unsigned int* ws_cnt = (unsigned int*)((char*)d_ws + sizeof(double));

    hipMemsetAsync(d_ws, 0, 16, stream);  // zero accumulator + done-counter
    mil_loss_kernel<<<NBLOCKS, NTHREADS, 0, stream>>>(y_prob, w, Y, out, ws_acc, ws_cnt);
}

// Round 3
// 66.388 us; speedup vs baseline: 1.3508x; 1.3508x over previous
//
#include <hip/hip_runtime.h>

// MIL loss, Y==1 path collapses to:
//   result = sum_e w[e] * ( S0 + hi_sum((e+1)>>10) + lo_sum((e+1)&1023) )
// with S0 = sum_j log(1-p_j), d[j] = log(p_j) - log(1-p_j),
//   lo_sum(m) = sum_{k=0..9, bit k of m} d[19-k]   (LDS table, 1024 entries)
//   hi_sum(h) = sum_{k=0..9, bit k of h} d[9-k]    (wave-uniform scalar: h == blockIdx)
// Y!=1 path: result = (2^20-1) * sum_j log(1-p_j).
//
// Kernel 1: 1024 blocks x 256 thr, block b owns subsets [b*1024, b*1024+1024),
//           writes one double partial per block to d_ws (no atomics, no init).
// Kernel 2: 1 block reduces the 1024 partials, applies the Y branch, writes out.

#define N_BITS    20
#define N_SUBSETS ((1u << N_BITS) - 1u)   // 1048575
#define NBLOCKS   1024
#define NTHREADS  256

__global__ __launch_bounds__(NTHREADS) void mil_partial(
    const float* __restrict__ y_prob,
    const float* __restrict__ w,
    double*      __restrict__ part)
{
    __shared__ float  s_d[N_BITS];    // d[j] = log p_j - log(1-p_j), j = column (MSB first)
    __shared__ float  s_l1[N_BITS];   // log(1-p_j)
    __shared__ float  t_lo[1024];
    __shared__ double s_wsum[NTHREADS / 64];

    const int      tid = threadIdx.x;
    const unsigned b   = blockIdx.x;

    if (tid < N_BITS) {
        float p = y_prob[tid];
        float lp = logf(p), l1 = logf(1.0f - p);
        s_d[tid]  = lp - l1;
        s_l1[tid] = l1;
    }
    __syncthreads();

    // lo-table: 4 entries per thread
    for (int m = tid; m < 1024; m += NTHREADS) {
        float a = 0.0f;
        #pragma unroll
        for (int k = 0; k < 10; ++k)
            if ((m >> k) & 1) a += s_d[19 - k];
        t_lo[m] = a;
    }

    // wave-uniform scalars: S0, hi_sum(b), hi_sum(b+1)
    float S0 = 0.0f;
    #pragma unroll
    for (int j = 0; j < N_BITS; ++j) S0 += s_l1[j];
    float hi0 = 0.0f, hi1 = 0.0f;
    #pragma unroll
    for (int k = 0; k < 10; ++k) {
        if ((b >> k) & 1)       hi0 += s_d[9 - k];
        if (((b + 1) >> k) & 1) hi1 += s_d[9 - k];
    }
    const float base0 = S0 + hi0;   // for idx in (b*1024, (b+1)*1024)
    const float base1 = S0 + hi1;   // for idx == (b+1)*1024 (lo==0, t_lo[0]==0)
    __syncthreads();

    // main dot: thread t handles elements b*1024 + 256j + t  (lane-consecutive
    // t_lo reads -> conflict-free; w loads fully coalesced dwords)
    double acc = 0.0;
    #pragma unroll
    for (int j = 0; j < 4; ++j) {
        unsigned e = b * 1024u + (unsigned)(j * NTHREADS) + (unsigned)tid;
        if (e < N_SUBSETS) {
            unsigned lo = (e + 1u) & 1023u;
            float v = lo ? (base0 + t_lo[lo]) : base1;
            acc += (double)(v * w[e]);
        }
    }

    // block reduction
    #pragma unroll
    for (int off = 32; off > 0; off >>= 1)
        acc += __shfl_down(acc, off, 64);
    const int wid = tid >> 6, lane = tid & 63;
    if (lane == 0) s_wsum[wid] = acc;
    __syncthreads();
    if (tid == 0)
        part[b] = s_wsum[0] + s_wsum[1] + s_wsum[2] + s_wsum[3];
}

__global__ __launch_bounds__(NTHREADS) void mil_final(
    const double* __restrict__ part,
    const float*  __restrict__ y_prob,
    const int*    __restrict__ Yp,
    float*        __restrict__ out)
{
    __shared__ double s_wsum[NTHREADS / 64];
    const int tid = threadIdx.x;

    double acc = part[tid] + part[tid + 256] + part[tid + 512] + part[tid + 768];
    #pragma unroll
    for (int off = 32; off > 0; off >>= 1)
        acc += __shfl_down(acc, off, 64);
    const int wid = tid >> 6, lane = tid & 63;
    if (lane == 0) s_wsum[wid] = acc;
    __syncthreads();

    if (tid == 0) {
        double total = s_wsum[0] + s_wsum[1] + s_wsum[2] + s_wsum[3];
        if (*Yp == 1) {
            *out = (float)total;
        } else {
            float s1 = 0.0f;
            #pragma unroll
            for (int j = 0; j < N_BITS; ++j) s1 += logf(1.0f - y_prob[j]);
            *out = (float)N_SUBSETS * s1;
        }
    }
}

extern "C" void kernel_launch(void* const* d_in, const int* in_sizes, int n_in,
                              void* d_out, int out_size, void* d_ws, size_t ws_size,
                              hipStream_t stream) {
    const float* y_prob = (const float*)d_in[0];
    const float* w      = (const float*)d_in[1];
    const int*   Y      = (const int*)d_in[2];
    // d_in[3] = bag_size (fixed at 20, baked into N_BITS)
    float*  out  = (float*)d_out;
    double* part = (double*)d_ws;   // 1024 doubles = 8 KB, fully written by
                                    // mil_partial before mil_final reads it

    mil_partial<<<NBLOCKS, NTHREADS, 0, stream>>>(y_prob, w, part);
    mil_final<<<1, NTHREADS, 0, stream>>>(part, y_prob, Y, out);
}